// Round 1
// baseline (418.000 us; speedup 1.0000x reference)
//
#include <hip/hip_runtime.h>
#include <math.h>

#define Bn 4
#define Nn 2048
#define Hn 8
#define HDn 32
#define Dn 256

typedef _Float16 h1;
typedef __attribute__((ext_vector_type(8))) _Float16 h8;
typedef __attribute__((ext_vector_type(4))) float fx4;

#define QSCALE 0.35355339059327373f  // 2/sqrt(HD): folded into q-side features

// ---------------------------------------------------------------------------
// Kernel 1: QKV projection (fp32 vector) + quantum feature map -> f16
//   qf[b,h,n,64] = QSCALE*[cos(q), sin(q)]   (scaled)
//   kf[b,h,n,64] =        [cos(k), sin(k)]
//   vT[b,h,d,n]  = v (transposed for PV B-fragment b128 loads)
// ---------------------------------------------------------------------------
__global__ __launch_bounds__(256) void proj_kernel(
    const float* __restrict__ x,
    const float* __restrict__ Wq, const float* __restrict__ bq,
    const float* __restrict__ Wk, const float* __restrict__ bk,
    const float* __restrict__ Wv, const float* __restrict__ bv,
    h1* __restrict__ qf, h1* __restrict__ kf, h1* __restrict__ vT)
{
    __shared__ float xsT[256][20];  // [d][row], pad 20 keeps float4 rows 16B-aligned
    const int t = threadIdx.x;
    const int r0 = blockIdx.x * 16;
#pragma unroll
    for (int i = 0; i < 16; ++i) xsT[t][i] = x[(size_t)(r0 + i) * 256 + t];
    __syncthreads();

    float aq[16], ak[16], av[16];
#pragma unroll
    for (int i = 0; i < 16; ++i) { aq[i] = 0.f; ak[i] = 0.f; av[i] = 0.f; }

    for (int d = 0; d < 256; ++d) {
        const float wq = Wq[d * 256 + t];
        const float wk = Wk[d * 256 + t];
        const float wv = Wv[d * 256 + t];
        float xv[16];
        *(float4*)&xv[0]  = *(const float4*)&xsT[d][0];
        *(float4*)&xv[4]  = *(const float4*)&xsT[d][4];
        *(float4*)&xv[8]  = *(const float4*)&xsT[d][8];
        *(float4*)&xv[12] = *(const float4*)&xsT[d][12];
#pragma unroll
        for (int i = 0; i < 16; ++i) {
            aq[i] = fmaf(xv[i], wq, aq[i]);
            ak[i] = fmaf(xv[i], wk, ak[i]);
            av[i] = fmaf(xv[i], wv, av[i]);
        }
    }

    const int h = t >> 5, dd = t & 31;
    const int b = r0 >> 11;
    const int n0 = r0 & (Nn - 1);
    const size_t fb = ((size_t)(b * Hn + h) * Nn + n0) * 64 + dd;
    h8 v0, v1;
#pragma unroll
    for (int i = 0; i < 16; ++i) {
        const float qq = aq[i] + bq[t];
        const float kk = ak[i] + bk[t];
        float sq, cq, sk, ck;
        __sincosf(qq, &sq, &cq);
        __sincosf(kk, &sk, &ck);
        const size_t qi = fb + (size_t)i * 64;
        qf[qi]      = (h1)(QSCALE * cq);
        qf[qi + 32] = (h1)(QSCALE * sq);
        kf[qi]      = (h1)ck;
        kf[qi + 32] = (h1)sk;
        const float vv = av[i] + bv[t];
        if (i < 8) v0[i] = (h1)vv; else v1[i - 8] = (h1)vv;
    }
    const size_t vb = ((size_t)(b * Hn + h) * HDn + dd) * Nn + n0;
    *(h8*)(vT + vb)     = v0;
    *(h8*)(vT + vb + 8) = v1;
}

// ---------------------------------------------------------------------------
// Kernel 2: fused attention. Block = (b, 32 q-rows), 8 waves = 8 heads.
// topo tile staged once in LDS (shared by all heads). MFMA 16x16x32 f16.
// Fragment layouts (verified on gfx950, learn_hip m89/m120):
//   A: A[m = lane&15][k = quad*8 + j]
//   B: B[k = quad*8 + j][n = lane&15]
//   C/D: row = quad*4 + reg, col = lane&15
// ---------------------------------------------------------------------------
__global__ __launch_bounds__(512) void attn_kernel(
    const h1* __restrict__ qf, const h1* __restrict__ kf, const h1* __restrict__ vT,
    const float* __restrict__ topo, float* __restrict__ y)
{
    __shared__ float tps[32][33];                 // topo tile [qrow][mcol]
    __shared__ __align__(16) h1 Pw[8][32][40];    // per-wave P transpose buffer (pad 40)

    const int b = blockIdx.y;
    const int n0 = blockIdx.x * 32;
    const int tid = threadIdx.x;
    const int h = tid >> 6;        // wave id = head
    const int lane = tid & 63;
    const int quad = lane >> 4;
    const int l15 = lane & 15;

    const h1* qfh = qf + (size_t)(b * Hn + h) * Nn * 64;
    const h1* kfh = kf + (size_t)(b * Hn + h) * Nn * 64;
    const h1* vTh = vT + (size_t)(b * Hn + h) * HDn * Nn;
    const float* tpb = topo + (size_t)b * Nn * Nn + (size_t)n0 * Nn;

    // Preload q A-fragments: [qsub][kstep]
    h8 qfr[2][2];
#pragma unroll
    for (int qs = 0; qs < 2; ++qs)
#pragma unroll
        for (int ks = 0; ks < 2; ++ks)
            qfr[qs][ks] = *(const h8*)(qfh + (size_t)(n0 + qs * 16 + l15) * 64 + ks * 32 + quad * 8);

    fx4 acc[2][2];
    float mrun[2][4], lrun[2][4];
#pragma unroll
    for (int qs = 0; qs < 2; ++qs) {
#pragma unroll
        for (int ds = 0; ds < 2; ++ds) acc[qs][ds] = (fx4){0.f, 0.f, 0.f, 0.f};
#pragma unroll
        for (int r = 0; r < 4; ++r) { mrun[qs][r] = -INFINITY; lrun[qs][r] = 0.f; }
    }

    const int srow = tid >> 4;
    const int scol = (tid & 15) * 2;

    for (int it = 0; it < Nn / 32; ++it) {
        const int m0 = it * 32;
        // stage topo tile (all 512 threads, 1 float2 each)
        {
            const float2 tv = *(const float2*)(tpb + (size_t)srow * Nn + m0 + scol);
            tps[srow][scol]     = tv.x;
            tps[srow][scol + 1] = tv.y;
        }
        __syncthreads();

        // K B-fragments straight from global (L1/L2-cached)
        h8 kfr[2][2];
#pragma unroll
        for (int ms = 0; ms < 2; ++ms)
#pragma unroll
            for (int ks = 0; ks < 2; ++ks)
                kfr[ms][ks] = *(const h8*)(kfh + (size_t)(m0 + ms * 16 + l15) * 64 + ks * 32 + quad * 8);

        // S = Qf @ Kf^T  (scale pre-folded into qf)
        fx4 S[2][2];
        const fx4 z4 = {0.f, 0.f, 0.f, 0.f};
#pragma unroll
        for (int qs = 0; qs < 2; ++qs)
#pragma unroll
            for (int ms = 0; ms < 2; ++ms) {
                fx4 tmp = __builtin_amdgcn_mfma_f32_16x16x32_f16(qfr[qs][0], kfr[ms][0], z4, 0, 0, 0);
                S[qs][ms] = __builtin_amdgcn_mfma_f32_16x16x32_f16(qfr[qs][1], kfr[ms][1], tmp, 0, 0, 0);
            }

        // multiply by topo (pre-softmax, per reference)
#pragma unroll
        for (int qs = 0; qs < 2; ++qs)
#pragma unroll
            for (int ms = 0; ms < 2; ++ms)
#pragma unroll
                for (int r = 0; r < 4; ++r)
                    S[qs][ms][r] *= tps[qs * 16 + quad * 4 + r][ms * 16 + l15];

        // online softmax per q-row (rows live in C-layout: row = quad*4+r)
#pragma unroll
        for (int qs = 0; qs < 2; ++qs) {
            float rm[4], p0[4], p1[4], rs[4], al[4];
#pragma unroll
            for (int r = 0; r < 4; ++r) rm[r] = fmaxf(S[qs][0][r], S[qs][1][r]);
#pragma unroll
            for (int off = 1; off <= 8; off <<= 1)
#pragma unroll
                for (int r = 0; r < 4; ++r) rm[r] = fmaxf(rm[r], __shfl_xor(rm[r], off));
#pragma unroll
            for (int r = 0; r < 4; ++r) {
                const float mn = fmaxf(mrun[qs][r], rm[r]);
                al[r] = __expf(mrun[qs][r] - mn);
                mrun[qs][r] = mn;
                p0[r] = __expf(S[qs][0][r] - mn);
                p1[r] = __expf(S[qs][1][r] - mn);
                rs[r] = p0[r] + p1[r];
            }
#pragma unroll
            for (int off = 1; off <= 8; off <<= 1)
#pragma unroll
                for (int r = 0; r < 4; ++r) rs[r] += __shfl_xor(rs[r], off);
#pragma unroll
            for (int r = 0; r < 4; ++r) {
                lrun[qs][r] = lrun[qs][r] * al[r] + rs[r];
                acc[qs][0][r] *= al[r];
                acc[qs][1][r] *= al[r];
                // P: C-layout -> LDS (intra-wave only, no barrier needed)
                Pw[h][qs * 16 + quad * 4 + r][l15]      = (h1)p0[r];
                Pw[h][qs * 16 + quad * 4 + r][16 + l15] = (h1)p1[r];
            }
        }
        __asm__ volatile("s_waitcnt lgkmcnt(0)" ::: "memory");

        // PV: A = P (A-layout from LDS), B = v via transposed vT (b128 global)
        h8 aP[2], bV[2];
#pragma unroll
        for (int qs = 0; qs < 2; ++qs)
            aP[qs] = *(const h8*)&Pw[h][qs * 16 + l15][quad * 8];
#pragma unroll
        for (int ds = 0; ds < 2; ++ds)
            bV[ds] = *(const h8*)(vTh + (size_t)(ds * 16 + l15) * Nn + m0 + quad * 8);
#pragma unroll
        for (int qs = 0; qs < 2; ++qs)
#pragma unroll
            for (int ds = 0; ds < 2; ++ds)
                acc[qs][ds] = __builtin_amdgcn_mfma_f32_16x16x32_f16(aP[qs], bV[ds], acc[qs][ds], 0, 0, 0);

        __syncthreads();  // protect tps before next iteration's overwrite
    }

    // epilogue: normalize and write y[b,n, h*32 + d] (f32)
#pragma unroll
    for (int qs = 0; qs < 2; ++qs)
#pragma unroll
        for (int r = 0; r < 4; ++r) {
            const float inv = 1.f / lrun[qs][r];
            const size_t row = (size_t)(b * Nn + n0 + qs * 16 + quad * 4 + r) * Dn + h * HDn;
            y[row + l15]      = acc[qs][0][r] * inv;
            y[row + 16 + l15] = acc[qs][1][r] * inv;
        }
}

// ---------------------------------------------------------------------------
// Kernel 3: output projection  out = y @ Wo + bo   (fp32 vector, 4x4 tile)
// ---------------------------------------------------------------------------
__global__ __launch_bounds__(256) void oproj_kernel(
    const float* __restrict__ y, const float* __restrict__ Wo,
    const float* __restrict__ bo, float* __restrict__ out)
{
    __shared__ float ysT[256][20];
    const int t = threadIdx.x;
    const int r0 = blockIdx.x * 16;
#pragma unroll
    for (int i = 0; i < 16; ++i) ysT[t][i] = y[(size_t)(r0 + i) * 256 + t];
    __syncthreads();

    const int cg = t & 63, rg = t >> 6;
    float acc[4][4];
#pragma unroll
    for (int i = 0; i < 4; ++i)
#pragma unroll
        for (int j = 0; j < 4; ++j) acc[i][j] = 0.f;

    for (int d = 0; d < 256; ++d) {
        const float4 yv = *(const float4*)&ysT[d][rg * 4];
        const float4 wv = *(const float4*)&Wo[d * 256 + cg * 4];
        const float yy[4] = {yv.x, yv.y, yv.z, yv.w};
        const float ww[4] = {wv.x, wv.y, wv.z, wv.w};
#pragma unroll
        for (int i = 0; i < 4; ++i)
#pragma unroll
            for (int j = 0; j < 4; ++j)
                acc[i][j] = fmaf(yy[i], ww[j], acc[i][j]);
    }
    const float4 bb = *(const float4*)&bo[cg * 4];
#pragma unroll
    for (int i = 0; i < 4; ++i) {
        float4 st;
        st.x = acc[i][0] + bb.x;
        st.y = acc[i][1] + bb.y;
        st.z = acc[i][2] + bb.z;
        st.w = acc[i][3] + bb.w;
        *(float4*)&out[(size_t)(r0 + rg * 4 + i) * 256 + cg * 4] = st;
    }
}

// ---------------------------------------------------------------------------
extern "C" void kernel_launch(void* const* d_in, const int* in_sizes, int n_in,
                              void* d_out, int out_size, void* d_ws, size_t ws_size,
                              hipStream_t stream)
{
    const float* x    = (const float*)d_in[0];
    const float* topo = (const float*)d_in[1];
    const float* Wq   = (const float*)d_in[2];
    const float* bq   = (const float*)d_in[3];
    const float* Wk   = (const float*)d_in[4];
    const float* bk   = (const float*)d_in[5];
    const float* Wv   = (const float*)d_in[6];
    const float* bv   = (const float*)d_in[7];
    const float* Wo   = (const float*)d_in[8];
    const float* bo   = (const float*)d_in[9];
    float* out = (float*)d_out;

    char* ws = (char*)d_ws;
    // ws layout: qf 8MB | kf 8MB | vT 4MB | y 8MB  (total 28MB)
    h1* qf   = (h1*)ws;
    h1* kf   = (h1*)(ws + (size_t)8 * 1024 * 1024);
    h1* vT   = (h1*)(ws + (size_t)16 * 1024 * 1024);
    float* y = (float*)(ws + (size_t)20 * 1024 * 1024);

    proj_kernel<<<dim3((Bn * Nn) / 16), 256, 0, stream>>>(x, Wq, bq, Wk, bk, Wv, bv, qf, kf, vT);
    attn_kernel<<<dim3(Nn / 32, Bn), 512, 0, stream>>>(qf, kf, vT, topo, y);
    oproj_kernel<<<dim3((Bn * Nn) / 16), 256, 0, stream>>>(y, Wo, bo, out);
}

// Round 2
// 327.468 us; speedup vs baseline: 1.2765x; 1.2765x over previous
//
#include <hip/hip_runtime.h>
#include <math.h>

#define Bn 4
#define Nn 2048
#define Hn 8
#define HDn 32
#define Dn 256
#define MHALF 1024  // m-split: 2 partials merged in oproj

typedef _Float16 h1;
typedef __attribute__((ext_vector_type(8))) _Float16 h8;
typedef __attribute__((ext_vector_type(4))) float fx4;

#define QSCALE 0.35355339059327373f  // 2/sqrt(HD): folded into q-side features
// |S| <= 2*HD/sqrt(HD) = 11.32 (topo in [0,1]) -> fixed softmax shift is safe:
// p = e^{S-4} in [2.2e-7, 1503] -- fits f16, no running max needed.
#define SOFTMAX_SHIFT 4.0f

// ---------------------------------------------------------------------------
// Kernel 1: QKV projection (fp32 vector) + quantum feature map -> f16
//   qf[b,h,n,64] = QSCALE*[cos(q), sin(q)]   (scaled)
//   kf[b,h,n,64] =        [cos(k), sin(k)]
//   vT[b,h,d,n]  = v (transposed for PV B-fragment b128 loads)
// ---------------------------------------------------------------------------
__global__ __launch_bounds__(256) void proj_kernel(
    const float* __restrict__ x,
    const float* __restrict__ Wq, const float* __restrict__ bq,
    const float* __restrict__ Wk, const float* __restrict__ bk,
    const float* __restrict__ Wv, const float* __restrict__ bv,
    h1* __restrict__ qf, h1* __restrict__ kf, h1* __restrict__ vT)
{
    __shared__ float xsT[256][20];  // [d][row], pad 20 keeps float4 rows 16B-aligned
    const int t = threadIdx.x;
    const int r0 = blockIdx.x * 16;
#pragma unroll
    for (int i = 0; i < 16; ++i) xsT[t][i] = x[(size_t)(r0 + i) * 256 + t];
    __syncthreads();

    float aq[16], ak[16], av[16];
#pragma unroll
    for (int i = 0; i < 16; ++i) { aq[i] = 0.f; ak[i] = 0.f; av[i] = 0.f; }

    for (int d = 0; d < 256; ++d) {
        const float wq = Wq[d * 256 + t];
        const float wk = Wk[d * 256 + t];
        const float wv = Wv[d * 256 + t];
        float xv[16];
        *(float4*)&xv[0]  = *(const float4*)&xsT[d][0];
        *(float4*)&xv[4]  = *(const float4*)&xsT[d][4];
        *(float4*)&xv[8]  = *(const float4*)&xsT[d][8];
        *(float4*)&xv[12] = *(const float4*)&xsT[d][12];
#pragma unroll
        for (int i = 0; i < 16; ++i) {
            aq[i] = fmaf(xv[i], wq, aq[i]);
            ak[i] = fmaf(xv[i], wk, ak[i]);
            av[i] = fmaf(xv[i], wv, av[i]);
        }
    }

    const int h = t >> 5, dd = t & 31;
    const int b = r0 >> 11;
    const int n0 = r0 & (Nn - 1);
    const size_t fb = ((size_t)(b * Hn + h) * Nn + n0) * 64 + dd;
    h8 v0, v1;
#pragma unroll
    for (int i = 0; i < 16; ++i) {
        const float qq = aq[i] + bq[t];
        const float kk = ak[i] + bk[t];
        float sq, cq, sk, ck;
        __sincosf(qq, &sq, &cq);
        __sincosf(kk, &sk, &ck);
        const size_t qi = fb + (size_t)i * 64;
        qf[qi]      = (h1)(QSCALE * cq);
        qf[qi + 32] = (h1)(QSCALE * sq);
        kf[qi]      = (h1)ck;
        kf[qi + 32] = (h1)sk;
        const float vv = av[i] + bv[t];
        if (i < 8) v0[i] = (h1)vv; else v1[i - 8] = (h1)vv;
    }
    const size_t vb = ((size_t)(b * Hn + h) * HDn + dd) * Nn + n0;
    *(h8*)(vT + vb)     = v0;
    *(h8*)(vT + vb + 8) = v1;
}

// ---------------------------------------------------------------------------
// Kernel 2: fused attention, barrier-free.
// Wave = (b, h, 32 q-rows, m-half). Block = 256 thr = 4 waves = 4 heads of the
// same (b, q-tile, m-half) -> identical topo reads hit L1. No __syncthreads.
// Fixed-shift softmax (no running max, no per-iter reductions): per-lane l
// partials reduced once in the epilogue. Partial (acc, l) per m-half; merged
// in oproj (valid because the shift is a shared constant).
// Fragment layouts (verified gfx950):
//   A: A[m = lane&15][k = quad*8 + j]
//   B: B[k = quad*8 + j][n = lane&15]
//   C/D: row = quad*4 + reg, col = lane&15
// ---------------------------------------------------------------------------
__global__ __launch_bounds__(256, 4) void attn_kernel(
    const h1* __restrict__ qf, const h1* __restrict__ kf, const h1* __restrict__ vT,
    const float* __restrict__ topo, float* __restrict__ pacc, float* __restrict__ pl)
{
    __shared__ __align__(16) h1 Pw[4][32][40];  // per-wave P transpose buffer

    const int b = blockIdx.y;
    const int n0 = blockIdx.x * 32;
    const int z = blockIdx.z;          // z = hg + 2*mh
    const int mh = z >> 1;
    const int tid = threadIdx.x;
    const int w = tid >> 6;
    const int h = (z & 1) * 4 + w;
    const int lane = tid & 63;
    const int quad = lane >> 4;
    const int l15 = lane & 15;

    const h1* qfh = qf + (size_t)(b * Hn + h) * Nn * 64;
    const h1* kfh = kf + (size_t)(b * Hn + h) * Nn * 64;
    const h1* vTh = vT + (size_t)(b * Hn + h) * HDn * Nn;
    const float* tpb = topo + (size_t)b * Nn * Nn + (size_t)n0 * Nn;

    // q A-fragments: [qsub][kstep]
    h8 qfr[2][2];
#pragma unroll
    for (int qs = 0; qs < 2; ++qs)
#pragma unroll
        for (int ks = 0; ks < 2; ++ks)
            qfr[qs][ks] = *(const h8*)(qfh + (size_t)(n0 + qs * 16 + l15) * 64 + ks * 32 + quad * 8);

    fx4 acc[2][2];
    float lsum[2][4];
#pragma unroll
    for (int qs = 0; qs < 2; ++qs) {
#pragma unroll
        for (int ds = 0; ds < 2; ++ds) acc[qs][ds] = (fx4){0.f, 0.f, 0.f, 0.f};
#pragma unroll
        for (int r = 0; r < 4; ++r) lsum[qs][r] = 0.f;
    }

    const int mbase = mh * MHALF;
    const fx4 z4 = {0.f, 0.f, 0.f, 0.f};

    for (int it = 0; it < MHALF / 32; ++it) {
        const int m0 = mbase + it * 32;

        // issue all global loads up front (compiler schedules per-use waits)
        h8 kfr[2][2];
#pragma unroll
        for (int ms = 0; ms < 2; ++ms)
#pragma unroll
            for (int ks = 0; ks < 2; ++ks)
                kfr[ms][ks] = *(const h8*)(kfh + (size_t)(m0 + ms * 16 + l15) * 64 + ks * 32 + quad * 8);
        h8 bV[2];
#pragma unroll
        for (int ds = 0; ds < 2; ++ds)
            bV[ds] = *(const h8*)(vTh + (size_t)(ds * 16 + l15) * Nn + m0 + quad * 8);
        float tpv[2][4][2];
#pragma unroll
        for (int qs = 0; qs < 2; ++qs)
#pragma unroll
            for (int r = 0; r < 4; ++r) {
                const float* tr = tpb + (size_t)(qs * 16 + quad * 4 + r) * Nn + m0 + l15;
                tpv[qs][r][0] = tr[0];
                tpv[qs][r][1] = tr[16];
            }

        // S = Qf @ Kf^T  (QSCALE pre-folded into qf)
        fx4 S[2][2];
#pragma unroll
        for (int qs = 0; qs < 2; ++qs)
#pragma unroll
            for (int ms = 0; ms < 2; ++ms) {
                fx4 tmp = __builtin_amdgcn_mfma_f32_16x16x32_f16(qfr[qs][0], kfr[ms][0], z4, 0, 0, 0);
                S[qs][ms] = __builtin_amdgcn_mfma_f32_16x16x32_f16(qfr[qs][1], kfr[ms][1], tmp, 0, 0, 0);
            }

        // p = e^{topo*S - 4}; accumulate per-lane l partials; P -> LDS (C->A)
#pragma unroll
        for (int qs = 0; qs < 2; ++qs)
#pragma unroll
            for (int ms = 0; ms < 2; ++ms)
#pragma unroll
                for (int r = 0; r < 4; ++r) {
                    const float p = __expf(fmaf(S[qs][ms][r], tpv[qs][r][ms], -SOFTMAX_SHIFT));
                    lsum[qs][r] += p;
                    Pw[w][qs * 16 + quad * 4 + r][ms * 16 + l15] = (h1)p;
                }
        __asm__ volatile("s_waitcnt lgkmcnt(0)" ::: "memory");

        // PV: A = P (A-layout from LDS), B = vT (contiguous b128)
        h8 aP[2];
#pragma unroll
        for (int qs = 0; qs < 2; ++qs)
            aP[qs] = *(const h8*)&Pw[w][qs * 16 + l15][quad * 8];
#pragma unroll
        for (int qs = 0; qs < 2; ++qs)
#pragma unroll
            for (int ds = 0; ds < 2; ++ds)
                acc[qs][ds] = __builtin_amdgcn_mfma_f32_16x16x32_f16(aP[qs], bV[ds], acc[qs][ds], 0, 0, 0);
    }

    // epilogue: one shuffle tree for l (cols live across 16 lanes), write partials
#pragma unroll
    for (int qs = 0; qs < 2; ++qs)
#pragma unroll
        for (int r = 0; r < 4; ++r)
#pragma unroll
            for (int off = 1; off <= 8; off <<= 1)
                lsum[qs][r] += __shfl_xor(lsum[qs][r], off);

    float* paccm = pacc + (size_t)mh * Bn * Nn * Dn;
    float* plm   = pl   + (size_t)mh * Bn * Nn * Hn;
#pragma unroll
    for (int qs = 0; qs < 2; ++qs)
#pragma unroll
        for (int r = 0; r < 4; ++r) {
            const size_t grow = (size_t)b * Nn + n0 + qs * 16 + quad * 4 + r;
            paccm[grow * Dn + h * HDn + l15]      = acc[qs][0][r];
            paccm[grow * Dn + h * HDn + 16 + l15] = acc[qs][1][r];
            if (l15 == 0) plm[grow * Hn + h] = lsum[qs][r];
        }
}

// ---------------------------------------------------------------------------
// Kernel 3: merge partials + output projection  out = y @ Wo + bo
// ---------------------------------------------------------------------------
__global__ __launch_bounds__(256) void oproj_kernel(
    const float* __restrict__ pacc, const float* __restrict__ pl,
    const float* __restrict__ Wo, const float* __restrict__ bo,
    float* __restrict__ out)
{
    __shared__ float ysT[256][20];
    const int t = threadIdx.x;
    const int r0 = blockIdx.x * 16;
    const int h = t >> 5;
    const float* pacc1 = pacc + (size_t)Bn * Nn * Dn;
    const float* pl1   = pl   + (size_t)Bn * Nn * Hn;
#pragma unroll
    for (int i = 0; i < 16; ++i) {
        const size_t row = (size_t)(r0 + i);
        const float l = pl[row * Hn + h] + pl1[row * Hn + h];
        const float inv = __builtin_amdgcn_rcpf(l);
        ysT[t][i] = (pacc[row * Dn + t] + pacc1[row * Dn + t]) * inv;
    }
    __syncthreads();

    const int cg = t & 63, rg = t >> 6;
    float acc[4][4];
#pragma unroll
    for (int i = 0; i < 4; ++i)
#pragma unroll
        for (int j = 0; j < 4; ++j) acc[i][j] = 0.f;

    for (int d = 0; d < 256; ++d) {
        const float4 yv = *(const float4*)&ysT[d][rg * 4];
        const float4 wv = *(const float4*)&Wo[d * 256 + cg * 4];
        const float yy[4] = {yv.x, yv.y, yv.z, yv.w};
        const float ww[4] = {wv.x, wv.y, wv.z, wv.w};
#pragma unroll
        for (int i = 0; i < 4; ++i)
#pragma unroll
            for (int j = 0; j < 4; ++j)
                acc[i][j] = fmaf(yy[i], ww[j], acc[i][j]);
    }
    const float4 bb = *(const float4*)&bo[cg * 4];
#pragma unroll
    for (int i = 0; i < 4; ++i) {
        float4 st;
        st.x = acc[i][0] + bb.x;
        st.y = acc[i][1] + bb.y;
        st.z = acc[i][2] + bb.z;
        st.w = acc[i][3] + bb.w;
        *(float4*)&out[(size_t)(r0 + rg * 4 + i) * 256 + cg * 4] = st;
    }
}

// ---------------------------------------------------------------------------
extern "C" void kernel_launch(void* const* d_in, const int* in_sizes, int n_in,
                              void* d_out, int out_size, void* d_ws, size_t ws_size,
                              hipStream_t stream)
{
    const float* x    = (const float*)d_in[0];
    const float* topo = (const float*)d_in[1];
    const float* Wq   = (const float*)d_in[2];
    const float* bq   = (const float*)d_in[3];
    const float* Wk   = (const float*)d_in[4];
    const float* bk   = (const float*)d_in[5];
    const float* Wv   = (const float*)d_in[6];
    const float* bv   = (const float*)d_in[7];
    const float* Wo   = (const float*)d_in[8];
    const float* bo   = (const float*)d_in[9];
    float* out = (float*)d_out;

    char* ws = (char*)d_ws;
    // ws layout: qf 8MB | kf 8MB | vT 4MB | pacc 2x8MB | pl 2x256KB  (~36.5MB)
    h1* qf     = (h1*)ws;
    h1* kf     = (h1*)(ws + (size_t)8 * 1024 * 1024);
    h1* vT     = (h1*)(ws + (size_t)16 * 1024 * 1024);
    float* pacc = (float*)(ws + (size_t)20 * 1024 * 1024);
    float* pl   = (float*)(ws + (size_t)36 * 1024 * 1024);

    proj_kernel<<<dim3((Bn * Nn) / 16), 256, 0, stream>>>(x, Wq, bq, Wk, bk, Wv, bv, qf, kf, vT);
    attn_kernel<<<dim3(Nn / 32, Bn, 4), 256, 0, stream>>>(qf, kf, vT, topo, pacc, pl);
    oproj_kernel<<<dim3((Bn * Nn) / 16), 256, 0, stream>>>(pacc, pl, Wo, bo, out);
}